// Round 1
// baseline (1866.350 us; speedup 1.0000x reference)
//
#include <hip/hip_runtime.h>
#include <hip/hip_bf16.h>
#include <math.h>

#define KNN 16
#define CIN 128
#define COUT 128
#define D2 64
#define EPS 1e-5f

// ---------- helpers ----------
static __device__ __forceinline__ unsigned int pack_bf2(float a, float b) {
  __hip_bfloat16 ha = __float2bfloat16(a);
  __hip_bfloat16 hb = __float2bfloat16(b);
  unsigned short ua, ub;
  __builtin_memcpy(&ua, &ha, 2);
  __builtin_memcpy(&ub, &hb, 2);
  return (unsigned int)ua | ((unsigned int)ub << 16);
}
static __device__ __forceinline__ float bf_lo(unsigned int u) { return __uint_as_float(u << 16); }
static __device__ __forceinline__ float bf_hi(unsigned int u) { return __uint_as_float(u & 0xffff0000u); }

static __device__ __forceinline__ float gelu_exact(float x) {
  return 0.5f * x * (1.0f + erff(x * 0.70710678118654752440f));
}

// ---------- kernel A: xp = x @ W, output bf16 (packed pairs as uint) ----------
__global__ __launch_bounds__(256) void k_proj(const float* __restrict__ x,
                                              const float* __restrict__ W,
                                              unsigned int* __restrict__ xp, int n) {
  __shared__ __align__(16) float Ws[CIN * COUT];
  int t = threadIdx.x;
  {
    const float4* W4 = (const float4*)W;
    float4* Ws4 = (float4*)Ws;
#pragma unroll
    for (int i = 0; i < 16; i++) Ws4[t + i * 256] = W4[t + i * 256];
  }
  __syncthreads();
  int gid = blockIdx.x * 256 + t;
  int r = gid >> 3;
  if (r >= n) return;
  int cb = (gid & 7) * 4;  // cols cb+{0..3} + g*32, g<4  (scattered -> conflict-free LDS)
  float acc[4][4];
#pragma unroll
  for (int g = 0; g < 4; g++)
#pragma unroll
    for (int j = 0; j < 4; j++) acc[g][j] = 0.f;

  const float4* xrow = (const float4*)(x + (size_t)r * CIN);
  for (int i4 = 0; i4 < CIN / 4; i4++) {
    float4 xv = xrow[i4];
    float xa[4] = {xv.x, xv.y, xv.z, xv.w};
#pragma unroll
    for (int j = 0; j < 4; j++) {
      float a = xa[j];
      int base = (i4 * 4 + j) * COUT + cb;
#pragma unroll
      for (int g = 0; g < 4; g++) {
        const float4 w = *(const float4*)&Ws[base + g * 32];
        acc[g][0] = fmaf(a, w.x, acc[g][0]);
        acc[g][1] = fmaf(a, w.y, acc[g][1]);
        acc[g][2] = fmaf(a, w.z, acc[g][2]);
        acc[g][3] = fmaf(a, w.w, acc[g][3]);
      }
    }
  }
  size_t rowb = (size_t)r * (COUT / 2);
#pragma unroll
  for (int g = 0; g < 4; g++) {
    int c = cb + g * 32;
    uint2 v;
    v.x = pack_bf2(acc[g][0], acc[g][1]);
    v.y = pack_bf2(acc[g][2], acc[g][3]);
    *(uint2*)&xp[rowb + (c >> 1)] = v;
  }
}

// ---------- kernel B: fused LFA (one wave per point) ----------
// LDS scratch per wave: buf[2176]: p0 = [0..1087] (16x68), p1 = [1088..2175] (16x68),
//                       g reuses [0..2111] (16x132).
__global__ __launch_bounds__(256) void k_lfa(
    const float* __restrict__ xyz,
    const unsigned int* __restrict__ xp,  // bf16 pairs, 64 uints per row
    const int* __restrict__ knn,
    const float* __restrict__ m1w, const float* __restrict__ m1b,
    const float* __restrict__ m2w, const float* __restrict__ m2b,
    const float* __restrict__ m3aw, const float* __restrict__ m3ab,
    const float* __restrict__ m3bw, const float* __restrict__ m3bb,
    float* __restrict__ xsmax, int n) {
  __shared__ __align__(16) float buf[4][2176];
  __shared__ __align__(16) float ploc_s[4][64];
  __shared__ float xyzs_s[4][16][3];
  __shared__ int knn_s[4][16];

  const int t = threadIdx.x;
  const int wv = t >> 6;
  const int l = t & 63;
  const int pt = blockIdx.x * 4 + wv;
  if (pt >= n) return;

  // ---- phase 1: indices + xyz diffs
  if (l < KNN) {
    int id = knn[(size_t)pt * KNN + l];
    knn_s[wv][l] = id;
    xyzs_s[wv][l][0] = xyz[(size_t)id * 3 + 0] - xyz[(size_t)pt * 3 + 0];
    xyzs_s[wv][l][1] = xyz[(size_t)id * 3 + 1] - xyz[(size_t)pt * 3 + 1];
    xyzs_s[wv][l][2] = xyz[(size_t)id * 3 + 2] - xyz[(size_t)pt * 3 + 2];
  }
  __syncthreads();

  // ---- phase 2: p0[k][d] (lane = d), p_local
  {
    float w0 = m1w[l], w1 = m1w[D2 + l], w2 = m1w[2 * D2 + l];
    float b1 = m1b[l];
    float ploc = -3.0e38f;
#pragma unroll
    for (int k = 0; k < KNN; k++) {
      float ax = xyzs_s[wv][k][0];
      float ay = xyzs_s[wv][k][1];
      float az = xyzs_s[wv][k][2];
      float v = fmaf(ax, w0, fmaf(ay, w1, fmaf(az, w2, b1)));
      buf[wv][k * 68 + l] = v;
      ploc = fmaxf(ploc, v);
    }
    ploc_s[wv][l] = ploc;
  }
  __syncthreads();

  // ---- phase 3: p1[k][d] = p0[k][:] @ m2 (lane = d)
  float p1r[KNN];
  {
    float b2 = m2b[l];
#pragma unroll
    for (int k = 0; k < KNN; k++) p1r[k] = b2;
    for (int i0 = 0; i0 < D2; i0 += 4) {
      float wA = m2w[(i0 + 0) * D2 + l];
      float wB = m2w[(i0 + 1) * D2 + l];
      float wC = m2w[(i0 + 2) * D2 + l];
      float wD = m2w[(i0 + 3) * D2 + l];
#pragma unroll
      for (int k = 0; k < KNN; k++) {
        float4 p = *(const float4*)&buf[wv][k * 68 + i0];
        p1r[k] = fmaf(p.x, wA, p1r[k]);
        p1r[k] = fmaf(p.y, wB, p1r[k]);
        p1r[k] = fmaf(p.z, wC, p1r[k]);
        p1r[k] = fmaf(p.w, wD, p1r[k]);
      }
    }
  }
#pragma unroll
  for (int k = 0; k < KNN; k++) buf[wv][1088 + k * 68 + l] = p1r[k];
  __syncthreads();

  // ---- phase 4: h = pfeat @ m3a + b.  lane = channel pair (2l, 2l+1).
  // pfeat = [p1 | p_local broadcast]  =>  h[k][c] = (p1-part) + hloc[c] (k-independent)
  const float2* A2 = (const float2*)m3aw;
  float h0[KNN], h1[KNN];
  {
    float2 b3 = ((const float2*)m3ab)[l];
    float h0loc = b3.x, h1loc = b3.y;
    for (int i0 = 0; i0 < D2; i0 += 4) {
      float4 p = *(const float4*)&ploc_s[wv][i0];
      float pa[4] = {p.x, p.y, p.z, p.w};
#pragma unroll
      for (int j = 0; j < 4; j++) {
        float2 w = A2[(D2 + i0 + j) * 64 + l];
        h0loc = fmaf(pa[j], w.x, h0loc);
        h1loc = fmaf(pa[j], w.y, h1loc);
      }
    }
#pragma unroll
    for (int k = 0; k < KNN; k++) { h0[k] = h0loc; h1[k] = h1loc; }
  }
  for (int i0 = 0; i0 < D2; i0 += 4) {
    float2 wA = A2[(i0 + 0) * 64 + l];
    float2 wB = A2[(i0 + 1) * 64 + l];
    float2 wC = A2[(i0 + 2) * 64 + l];
    float2 wD = A2[(i0 + 3) * 64 + l];
#pragma unroll
    for (int k = 0; k < KNN; k++) {
      float4 p = *(const float4*)&buf[wv][1088 + k * 68 + i0];
      h0[k] = fmaf(p.x, wA.x, h0[k]); h1[k] = fmaf(p.x, wA.y, h1[k]);
      h0[k] = fmaf(p.y, wB.x, h0[k]); h1[k] = fmaf(p.y, wB.y, h1[k]);
      h0[k] = fmaf(p.z, wC.x, h0[k]); h1[k] = fmaf(p.z, wC.y, h1[k]);
      h0[k] = fmaf(p.w, wD.x, h0[k]); h1[k] = fmaf(p.w, wD.y, h1[k]);
    }
  }
  __syncthreads();  // all p1 reads done before g overwrites buf

  // gelu -> g into buf (16 x 132)
#pragma unroll
  for (int k = 0; k < KNN; k++) {
    float2 g;
    g.x = gelu_exact(h0[k]);
    g.y = gelu_exact(h1[k]);
    *(float2*)&buf[wv][k * 132 + 2 * l] = g;
  }
  __syncthreads();

  // ---- phase 5: pe = g @ m3b + b, then gather xp and max-reduce
  const float2* B2 = (const float2*)m3bw;
  float e0[KNN], e1[KNN];
  {
    float2 b3 = ((const float2*)m3bb)[l];
#pragma unroll
    for (int k = 0; k < KNN; k++) { e0[k] = b3.x; e1[k] = b3.y; }
  }
  for (int i0 = 0; i0 < COUT; i0 += 4) {
    float2 wA = B2[(i0 + 0) * 64 + l];
    float2 wB = B2[(i0 + 1) * 64 + l];
    float2 wC = B2[(i0 + 2) * 64 + l];
    float2 wD = B2[(i0 + 3) * 64 + l];
#pragma unroll
    for (int k = 0; k < KNN; k++) {
      float4 g = *(const float4*)&buf[wv][k * 132 + i0];
      e0[k] = fmaf(g.x, wA.x, e0[k]); e1[k] = fmaf(g.x, wA.y, e1[k]);
      e0[k] = fmaf(g.y, wB.x, e0[k]); e1[k] = fmaf(g.y, wB.y, e1[k]);
      e0[k] = fmaf(g.z, wC.x, e0[k]); e1[k] = fmaf(g.z, wC.y, e1[k]);
      e0[k] = fmaf(g.w, wD.x, e0[k]); e1[k] = fmaf(g.w, wD.y, e1[k]);
    }
  }

  unsigned int pn = xp[(size_t)pt * 64 + l];
  float xn0 = bf_lo(pn), xn1 = bf_hi(pn);
  float m0 = -3.0e38f, m1v = -3.0e38f;
#pragma unroll
  for (int k = 0; k < KNN; k++) {
    int id = knn_s[wv][k];
    unsigned int pk = xp[(size_t)id * 64 + l];
    float v0 = bf_lo(pk) - xn0 + e0[k];
    float v1 = bf_hi(pk) - xn1 + e1[k];
    m0 = fmaxf(m0, v0);
    m1v = fmaxf(m1v, v1);
  }
  float2 o;
  o.x = m0;
  o.y = m1v;
  *(float2*)&xsmax[(size_t)pt * COUT + 2 * l] = o;
}

// ---------- kernel C1: batch-norm statistics ----------
__global__ __launch_bounds__(256) void k_bnstats(const float* __restrict__ xs,
                                                 float* __restrict__ sums, int n) {
  int t = threadIdx.x;
  int c = t & 127;
  int h = t >> 7;
  float s = 0.f, s2 = 0.f;
  for (int r = blockIdx.x * 2 + h; r < n; r += gridDim.x * 2) {
    float v = xs[(size_t)r * COUT + c];
    s += v;
    s2 += v * v;
  }
  __shared__ float red[256];
  red[t] = s;
  __syncthreads();
  if (h == 0) atomicAdd(&sums[c], s + red[t + 128]);
  __syncthreads();
  red[t] = s2;
  __syncthreads();
  if (h == 0) atomicAdd(&sums[128 + c], s2 + red[t + 128]);
}

// ---------- kernel C2: normalize ----------
__global__ __launch_bounds__(256) void k_bnnorm(const float* __restrict__ xs,
                                                const float* __restrict__ sums,
                                                const float* __restrict__ gamma,
                                                const float* __restrict__ beta,
                                                float* __restrict__ out, int n) {
  size_t i = (size_t)blockIdx.x * 256 + threadIdx.x;  // float4 index
  size_t total4 = (size_t)n * (COUT / 4);
  if (i >= total4) return;
  int c = (int)((i * 4) & (COUT - 1));
  float4 v = ((const float4*)xs)[i];
  float4 sm = *(const float4*)&sums[c];
  float4 sq = *(const float4*)&sums[128 + c];
  float4 gm = *(const float4*)&gamma[c];
  float4 bt = *(const float4*)&beta[c];
  float inv_n = 1.0f / (float)n;
  float4 o;
  {
    float mean = sm.x * inv_n, var = sq.x * inv_n - mean * mean;
    o.x = (v.x - mean) * rsqrtf(var + EPS) * gm.x + bt.x;
  }
  {
    float mean = sm.y * inv_n, var = sq.y * inv_n - mean * mean;
    o.y = (v.y - mean) * rsqrtf(var + EPS) * gm.y + bt.y;
  }
  {
    float mean = sm.z * inv_n, var = sq.z * inv_n - mean * mean;
    o.z = (v.z - mean) * rsqrtf(var + EPS) * gm.z + bt.z;
  }
  {
    float mean = sm.w * inv_n, var = sq.w * inv_n - mean * mean;
    o.w = (v.w - mean) * rsqrtf(var + EPS) * gm.w + bt.w;
  }
  ((float4*)out)[i] = o;
}

// ---------- launch ----------
extern "C" void kernel_launch(void* const* d_in, const int* in_sizes, int n_in,
                              void* d_out, int out_size, void* d_ws, size_t ws_size,
                              hipStream_t stream) {
  const float* xyz = (const float*)d_in[0];
  const float* x = (const float*)d_in[1];
  const int* knn = (const int*)d_in[2];
  const float* W = (const float*)d_in[3];
  const float* m1w = (const float*)d_in[4];
  const float* m1b = (const float*)d_in[5];
  const float* m2w = (const float*)d_in[6];
  const float* m2b = (const float*)d_in[7];
  const float* m3aw = (const float*)d_in[8];
  const float* m3ab = (const float*)d_in[9];
  const float* m3bw = (const float*)d_in[10];
  const float* m3bb = (const float*)d_in[11];
  const float* gamma = (const float*)d_in[12];
  const float* beta = (const float*)d_in[13];
  float* out = (float*)d_out;

  int n = in_sizes[0] / 3;  // N points

  char* ws = (char*)d_ws;
  unsigned int* xp = (unsigned int*)ws;  // bf16 xp, n*256 bytes
  size_t off = (((size_t)n * 256) + 255) & ~(size_t)255;
  float* xsmax = (float*)(ws + off);
  size_t off2 = off + ((((size_t)n * COUT * 4) + 255) & ~(size_t)255);
  float* sums = (float*)(ws + off2);  // 256 floats: sum | sumsq

  hipMemsetAsync(sums, 0, 256 * sizeof(float), stream);
  k_proj<<<(n * 8 + 255) / 256, 256, 0, stream>>>(x, W, xp, n);
  k_lfa<<<(n + 3) / 4, 256, 0, stream>>>(xyz, xp, knn, m1w, m1b, m2w, m2b,
                                         m3aw, m3ab, m3bw, m3bb, xsmax, n);
  k_bnstats<<<512, 256, 0, stream>>>(xsmax, sums, n);
  k_bnnorm<<<(int)(((size_t)n * (COUT / 4) + 255) / 256), 256, 0, stream>>>(
      xsmax, sums, gamma, beta, out, n);
}

// Round 2
// 1497.427 us; speedup vs baseline: 1.2464x; 1.2464x over previous
//
#include <hip/hip_runtime.h>
#include <hip/hip_bf16.h>
#include <math.h>

#define KNN 16
#define CIN 128
#define COUT 128
#define D2 64
#define EPS 1e-5f

typedef __attribute__((ext_vector_type(8))) short short8;
typedef __attribute__((ext_vector_type(4))) float f32x4;
typedef unsigned int u32;
typedef unsigned short u16;

union S8U { short8 s; u32 u[4]; };

#define MFMA16(a, b, c) __builtin_amdgcn_mfma_f32_16x16x32_bf16((a), (b), (c), 0, 0, 0)

static __device__ __forceinline__ u16 f2bf(float f) {
  __hip_bfloat16 h = __float2bfloat16(f);
  u16 u; __builtin_memcpy(&u, &h, 2); return u;
}
static __device__ __forceinline__ u32 pack2(float a, float b) {
  return (u32)f2bf(a) | ((u32)f2bf(b) << 16);
}
static __device__ __forceinline__ float bf_lo(u32 u) { return __uint_as_float(u << 16); }
static __device__ __forceinline__ float bf_hi(u32 u) { return __uint_as_float(u & 0xffff0000u); }
static __device__ __forceinline__ float gelu_exact(float x) {
  return 0.5f * x * (1.0f + erff(x * 0.70710678118654752440f));
}

// ---------- k_pack: weights -> MFMA A-operand fragments (bf16) ----------
// Fragment = A-frag of W^T: element (lane l, j) = W[(s*32 + (l>>4)*8 + j)][mt*16 + (l&15)]
// pk layout (each frag 512 u16 = 1 KB):
//   f in [0,8):   m2  frags, f = mt*2 + s   (mt<4, s<2)
//   f in [8,40):  m3a frags, f-8  = mt*4 + s (mt<8, s<4)
//   f in [40,72): m3b frags, f-40 = mt*4 + s
__global__ __launch_bounds__(256) void k_pack(const float* __restrict__ m2w,
                                              const float* __restrict__ m3aw,
                                              const float* __restrict__ m3bw,
                                              u16* __restrict__ pk) {
  for (int e = blockIdx.x * 256 + threadIdx.x; e < 72 * 512; e += gridDim.x * 256) {
    int f = e >> 9;
    int le = e & 511;
    int l = le >> 3, j = le & 7;
    int q = l >> 4, m = l & 15;
    float v;
    if (f < 8) {
      int mt = f >> 1, s = f & 1;
      v = m2w[(s * 32 + q * 8 + j) * 64 + mt * 16 + m];
    } else if (f < 40) {
      int ff = f - 8; int mt = ff >> 2, s = ff & 3;
      v = m3aw[(s * 32 + q * 8 + j) * 128 + mt * 16 + m];
    } else {
      int ff = f - 40; int mt = ff >> 2, s = ff & 3;
      v = m3bw[(s * 32 + q * 8 + j) * 128 + mt * 16 + m];
    }
    pk[e] = f2bf(v);
  }
}

// ---------- k_proj: xp = x @ W, output bf16 pairs ----------
__global__ __launch_bounds__(256) void k_proj(const float* __restrict__ x,
                                              const float* __restrict__ W,
                                              u32* __restrict__ xp, int n) {
  __shared__ __align__(16) float Ws[CIN * COUT];
  int t = threadIdx.x;
  {
    const float4* W4 = (const float4*)W;
    float4* Ws4 = (float4*)Ws;
#pragma unroll
    for (int i = 0; i < 16; i++) Ws4[t + i * 256] = W4[t + i * 256];
  }
  __syncthreads();
  int gid = blockIdx.x * 256 + t;
  int r = gid >> 3;
  if (r >= n) return;
  int cb = (gid & 7) * 4;
  float acc[4][4];
#pragma unroll
  for (int g = 0; g < 4; g++)
#pragma unroll
    for (int j = 0; j < 4; j++) acc[g][j] = 0.f;
  const float4* xrow = (const float4*)(x + (size_t)r * CIN);
  for (int i4 = 0; i4 < CIN / 4; i4++) {
    float4 xv = xrow[i4];
    float xa[4] = {xv.x, xv.y, xv.z, xv.w};
#pragma unroll
    for (int j = 0; j < 4; j++) {
      float a = xa[j];
      int base = (i4 * 4 + j) * COUT + cb;
#pragma unroll
      for (int g = 0; g < 4; g++) {
        const float4 w = *(const float4*)&Ws[base + g * 32];
        acc[g][0] = fmaf(a, w.x, acc[g][0]);
        acc[g][1] = fmaf(a, w.y, acc[g][1]);
        acc[g][2] = fmaf(a, w.z, acc[g][2]);
        acc[g][3] = fmaf(a, w.w, acc[g][3]);
      }
    }
  }
  size_t rowb = (size_t)r * (COUT / 2);
#pragma unroll
  for (int g = 0; g < 4; g++) {
    int c = cb + g * 32;
    uint2 v;
    v.x = pack2(acc[g][0], acc[g][1]);
    v.y = pack2(acc[g][2], acc[g][3]);
    *(uint2*)&xp[rowb + (c >> 1)] = v;
  }
}

// ---------- k_lfa: MFMA fused NCA + gather + max ----------
// One wave per point (grid-stride). Transposed matmuls:
//   p1^T = m2^T @ p0^T ; h^T = m3a^T @ pfeat^T ; pe^T = m3b^T @ g^T
// A-operands = prepacked weight frags (global, L1/L2-hot).
// B-operands = activation frags in A-layout-of-activation:
//   lane l holds act[m = l&15][s*32 + (l>>4)*8 + j].
// C/D layout: lane reg r holds Z[k = l&15][c = mt*16 + (l>>4)*4 + r].
__global__ __launch_bounds__(256, 2) void k_lfa(
    const float* __restrict__ xyz, const u32* __restrict__ xp,
    const int* __restrict__ knn,
    const float* __restrict__ m1w, const float* __restrict__ m1b,
    const u16* __restrict__ pk,
    const float* __restrict__ m2b, const float* __restrict__ m3ab,
    const float* __restrict__ m3bb,
    float* __restrict__ xsmax, int n) {
  // per-wave scratch: 16 rows x 136 u16 (272 B stride, +16B pad vs 256 for 2-way-free banks)
  __shared__ u16 sc[4][16 * 136];
  __shared__ int knn_s[4][16];

  const int t = threadIdx.x, wv = t >> 6, l = t & 63;
  const int q = l >> 4, m = l & 15;
  const short8* pkf = (const short8*)pk;
  char* scb = (char*)&sc[wv][0];

  // m2 frags resident in regs (8 x 16B/lane)
  short8 m2f[8];
#pragma unroll
  for (int f = 0; f < 8; f++) m2f[f] = pkf[f * 64 + l];

  // m1 weights per lane: col c(s,j) = s*32 + q*8 + j
  float w1x[16], w1y[16], w1z[16], w1b[16];
#pragma unroll
  for (int s = 0; s < 2; s++)
#pragma unroll
    for (int j = 0; j < 8; j++) {
      int c = s * 32 + q * 8 + j;
      w1x[s * 8 + j] = m1w[c];
      w1y[s * 8 + j] = m1w[D2 + c];
      w1z[s * 8 + j] = m1w[2 * D2 + c];
      w1b[s * 8 + j] = m1b[c];
    }

  const int nw = gridDim.x * 4;
  for (int pt = blockIdx.x * 4 + wv; pt < n; pt += nw) {
    // ---- knn + gather prefetch (lane = channel pair 2l,2l+1)
    int kid = knn[(size_t)pt * KNN + m];  // lane m's neighbor (dup across quads)
    if (q == 0) knn_s[wv][m] = kid;
    u32 gv[KNN];
#pragma unroll
    for (int k = 0; k < KNN; k++) {
      int r = knn_s[wv][k];
      gv[k] = xp[(size_t)r * 64 + l];
    }
    u32 selfv = xp[(size_t)pt * 64 + l];

    // ---- xyz diff for row m
    float px = xyz[(size_t)pt * 3 + 0], py = xyz[(size_t)pt * 3 + 1], pz = xyz[(size_t)pt * 3 + 2];
    float ax = xyz[(size_t)kid * 3 + 0] - px;
    float ay = xyz[(size_t)kid * 3 + 1] - py;
    float az = xyz[(size_t)kid * 3 + 2] - pz;

    // ---- p0[m][c] in B-frag layout (registers)
    float p0v[16];
#pragma unroll
    for (int i = 0; i < 16; i++)
      p0v[i] = fmaf(ax, w1x[i], fmaf(ay, w1y[i], fmaf(az, w1z[i], w1b[i])));
    S8U bp0[2];
#pragma unroll
    for (int s = 0; s < 2; s++)
#pragma unroll
      for (int jj = 0; jj < 4; jj++)
        bp0[s].u[jj] = pack2(p0v[s * 8 + jj * 2], p0v[s * 8 + jj * 2 + 1]);

    // ---- p_local = max over k (= lane low 4 bits) of p0; lands broadcast in all lanes
    S8U bpl[2];
#pragma unroll
    for (int s = 0; s < 2; s++)
#pragma unroll
      for (int jj = 0; jj < 4; jj++) {
        float v0 = p0v[s * 8 + jj * 2], v1 = p0v[s * 8 + jj * 2 + 1];
        v0 = fmaxf(v0, __shfl_xor(v0, 1)); v1 = fmaxf(v1, __shfl_xor(v1, 1));
        v0 = fmaxf(v0, __shfl_xor(v0, 2)); v1 = fmaxf(v1, __shfl_xor(v1, 2));
        v0 = fmaxf(v0, __shfl_xor(v0, 4)); v1 = fmaxf(v1, __shfl_xor(v1, 4));
        v0 = fmaxf(v0, __shfl_xor(v0, 8)); v1 = fmaxf(v1, __shfl_xor(v1, 8));
        bpl[s].u[jj] = pack2(v0, v1);
      }

    // ---- p1^T = m2^T @ p0^T (+bias via C init); write bf16 to scratch (C->A transform)
#pragma unroll
    for (int mt = 0; mt < 4; mt++) {
      float4 bb = *(const float4*)&m2b[mt * 16 + q * 4];
      f32x4 acc = {bb.x, bb.y, bb.z, bb.w};
      acc = MFMA16(m2f[mt * 2 + 0], bp0[0].s, acc);
      acc = MFMA16(m2f[mt * 2 + 1], bp0[1].s, acc);
      uint2 w;
      w.x = pack2(acc[0], acc[1]);
      w.y = pack2(acc[2], acc[3]);
      *(uint2*)(scb + m * 272 + (mt * 16 + q * 4) * 2) = w;  // row k=m, cols mt*16+q*4..+3
    }
    // pfeat B-frags: s=0,1 from p1 scratch; s=2,3 = p_local regs
    short8 bpf0 = *(const short8*)(scb + m * 272 + q * 16);
    short8 bpf1 = *(const short8*)(scb + m * 272 + 64 + q * 16);

    // ---- h^T = m3a^T @ pfeat^T (+bias); gelu; write g bf16 to scratch
#pragma unroll
    for (int mt = 0; mt < 8; mt++) {
      float4 bb = *(const float4*)&m3ab[mt * 16 + q * 4];
      f32x4 acc = {bb.x, bb.y, bb.z, bb.w};
      acc = MFMA16(pkf[(8 + mt * 4 + 0) * 64 + l], bpf0, acc);
      acc = MFMA16(pkf[(8 + mt * 4 + 1) * 64 + l], bpf1, acc);
      acc = MFMA16(pkf[(8 + mt * 4 + 2) * 64 + l], bpl[0].s, acc);
      acc = MFMA16(pkf[(8 + mt * 4 + 3) * 64 + l], bpl[1].s, acc);
      uint2 w;
      w.x = pack2(gelu_exact(acc[0]), gelu_exact(acc[1]));
      w.y = pack2(gelu_exact(acc[2]), gelu_exact(acc[3]));
      *(uint2*)(scb + m * 272 + (mt * 16 + q * 4) * 2) = w;
    }
    short8 bg0 = *(const short8*)(scb + m * 272 + 0 + q * 16);
    short8 bg1 = *(const short8*)(scb + m * 272 + 64 + q * 16);
    short8 bg2 = *(const short8*)(scb + m * 272 + 128 + q * 16);
    short8 bg3 = *(const short8*)(scb + m * 272 + 192 + q * 16);

    // ---- pe^T = m3b^T @ g^T (+bias); keep all 8 tiles in regs, then write bf16
    f32x4 pe[8];
#pragma unroll
    for (int mt = 0; mt < 8; mt++) {
      float4 bb = *(const float4*)&m3bb[mt * 16 + q * 4];
      f32x4 acc = {bb.x, bb.y, bb.z, bb.w};
      acc = MFMA16(pkf[(40 + mt * 4 + 0) * 64 + l], bg0, acc);
      acc = MFMA16(pkf[(40 + mt * 4 + 1) * 64 + l], bg1, acc);
      acc = MFMA16(pkf[(40 + mt * 4 + 2) * 64 + l], bg2, acc);
      acc = MFMA16(pkf[(40 + mt * 4 + 3) * 64 + l], bg3, acc);
      pe[mt] = acc;
    }
#pragma unroll
    for (int mt = 0; mt < 8; mt++) {
      uint2 w;
      w.x = pack2(pe[mt][0], pe[mt][1]);
      w.y = pack2(pe[mt][2], pe[mt][3]);
      *(uint2*)(scb + m * 272 + (mt * 16 + q * 4) * 2) = w;
    }

    // ---- epilogue: max_k(xp_k + pe_k) - xp_self, lane = channel pair (2l, 2l+1)
    float mx0 = -3.0e38f, mx1 = -3.0e38f;
#pragma unroll
    for (int k = 0; k < KNN; k++) {
      u32 pw = *(const u32*)(scb + k * 272 + l * 4);
      float v0 = bf_lo(gv[k]) + bf_lo(pw);
      float v1 = bf_hi(gv[k]) + bf_hi(pw);
      mx0 = fmaxf(mx0, v0);
      mx1 = fmaxf(mx1, v1);
    }
    float2 o;
    o.x = mx0 - bf_lo(selfv);
    o.y = mx1 - bf_hi(selfv);
    *(float2*)&xsmax[(size_t)pt * COUT + 2 * l] = o;
  }
}

// ---------- BN stats ----------
__global__ __launch_bounds__(256) void k_bnstats(const float* __restrict__ xs,
                                                 float* __restrict__ sums, int n) {
  int t = threadIdx.x;
  int c = t & 127;
  int h = t >> 7;
  float s = 0.f, s2 = 0.f;
  for (int r = blockIdx.x * 2 + h; r < n; r += gridDim.x * 2) {
    float v = xs[(size_t)r * COUT + c];
    s += v;
    s2 += v * v;
  }
  __shared__ float red[256];
  red[t] = s;
  __syncthreads();
  if (h == 0) atomicAdd(&sums[c], s + red[t + 128]);
  __syncthreads();
  red[t] = s2;
  __syncthreads();
  if (h == 0) atomicAdd(&sums[128 + c], s2 + red[t + 128]);
}

// ---------- BN normalize ----------
__global__ __launch_bounds__(256) void k_bnnorm(const float* __restrict__ xs,
                                                const float* __restrict__ sums,
                                                const float* __restrict__ gamma,
                                                const float* __restrict__ beta,
                                                float* __restrict__ out, int n) {
  size_t i = (size_t)blockIdx.x * 256 + threadIdx.x;
  size_t total4 = (size_t)n * (COUT / 4);
  if (i >= total4) return;
  int c = (int)((i * 4) & (COUT - 1));
  float4 v = ((const float4*)xs)[i];
  float4 sm = *(const float4*)&sums[c];
  float4 sq = *(const float4*)&sums[128 + c];
  float4 gm = *(const float4*)&gamma[c];
  float4 bt = *(const float4*)&beta[c];
  float inv_n = 1.0f / (float)n;
  float4 o;
  { float mean = sm.x * inv_n, var = sq.x * inv_n - mean * mean;
    o.x = (v.x - mean) * rsqrtf(var + EPS) * gm.x + bt.x; }
  { float mean = sm.y * inv_n, var = sq.y * inv_n - mean * mean;
    o.y = (v.y - mean) * rsqrtf(var + EPS) * gm.y + bt.y; }
  { float mean = sm.z * inv_n, var = sq.z * inv_n - mean * mean;
    o.z = (v.z - mean) * rsqrtf(var + EPS) * gm.z + bt.z; }
  { float mean = sm.w * inv_n, var = sq.w * inv_n - mean * mean;
    o.w = (v.w - mean) * rsqrtf(var + EPS) * gm.w + bt.w; }
  ((float4*)out)[i] = o;
}

// ---------- launch ----------
extern "C" void kernel_launch(void* const* d_in, const int* in_sizes, int n_in,
                              void* d_out, int out_size, void* d_ws, size_t ws_size,
                              hipStream_t stream) {
  const float* xyz = (const float*)d_in[0];
  const float* x = (const float*)d_in[1];
  const int* knn = (const int*)d_in[2];
  const float* W = (const float*)d_in[3];
  const float* m1w = (const float*)d_in[4];
  const float* m1b = (const float*)d_in[5];
  const float* m2w = (const float*)d_in[6];
  const float* m2b = (const float*)d_in[7];
  const float* m3aw = (const float*)d_in[8];
  const float* m3ab = (const float*)d_in[9];
  const float* m3bw = (const float*)d_in[10];
  const float* m3bb = (const float*)d_in[11];
  const float* gamma = (const float*)d_in[12];
  const float* beta = (const float*)d_in[13];
  float* out = (float*)d_out;

  int n = in_sizes[0] / 3;

  char* ws = (char*)d_ws;
  u16* pk = (u16*)ws;                       // 72 frags * 1 KB = 73728 B (256-aligned)
  size_t o1 = 73728;
  u32* xp = (u32*)(ws + o1);                // n * 256 B
  size_t o2 = o1 + (((size_t)n * 256 + 255) & ~(size_t)255);
  float* xsm = (float*)(ws + o2);           // n * 512 B
  size_t o3 = o2 + (((size_t)n * 512 + 255) & ~(size_t)255);
  float* sums = (float*)(ws + o3);          // 256 floats

  hipMemsetAsync(sums, 0, 256 * sizeof(float), stream);
  k_pack<<<144, 256, 0, stream>>>(m2w, m3aw, m3bw, pk);
  k_proj<<<(n * 8 + 255) / 256, 256, 0, stream>>>(x, W, xp, n);
  k_lfa<<<512, 256, 0, stream>>>(xyz, xp, knn, m1w, m1b, pk, m2b, m3ab, m3bb, xsm, n);
  k_bnstats<<<512, 256, 0, stream>>>(xsm, sums, n);
  k_bnnorm<<<(int)(((size_t)n * (COUT / 4) + 255) / 256), 256, 0, stream>>>(
      xsm, sums, gamma, beta, out, n);
}

// Round 3
// 1093.144 us; speedup vs baseline: 1.7073x; 1.3698x over previous
//
#include <hip/hip_runtime.h>
#include <hip/hip_bf16.h>
#include <math.h>

#define KNN 16
#define CIN 128
#define COUT 128
#define D2 64
#define EPS 1e-5f

typedef __attribute__((ext_vector_type(8))) short short8;
typedef __attribute__((ext_vector_type(4))) float f32x4;
typedef unsigned int u32;
typedef unsigned short u16;

union S8U { short8 s; u32 u[4]; };

#define MFMA16(a, b, c) __builtin_amdgcn_mfma_f32_16x16x32_bf16((a), (b), (c), 0, 0, 0)

static __device__ __forceinline__ u16 f2bf(float f) {
  __hip_bfloat16 h = __float2bfloat16(f);
  u16 u; __builtin_memcpy(&u, &h, 2); return u;
}
static __device__ __forceinline__ u32 pack2(float a, float b) {
  return (u32)f2bf(a) | ((u32)f2bf(b) << 16);
}
static __device__ __forceinline__ float bf_lo(u32 u) { return __uint_as_float(u << 16); }
static __device__ __forceinline__ float bf_hi(u32 u) { return __uint_as_float(u & 0xffff0000u); }

// tanh-form gelu via sigmoid: gelu(x) ~= x * sigmoid(1.5957691*(x + 0.044715x^3))
static __device__ __forceinline__ float gelu_fast(float x) {
  float x2 = x * x;
  float p = fmaf(0.044715f * x2, x, x);
  float e = __expf(-1.5957691216f * p);
  return x * __builtin_amdgcn_rcpf(1.0f + e);
}

// max-reduce over the 16-lane DPP row (lanes l..l|15) via xor1, xor2, half-mirror, ror8
template <int CTRL>
static __device__ __forceinline__ float dppmax(float v) {
  int s = __builtin_bit_cast(int, v);
  int t = __builtin_amdgcn_update_dpp(s, s, CTRL, 0xf, 0xf, true);
  return fmaxf(v, __builtin_bit_cast(float, t));
}
static __device__ __forceinline__ float rowmax16(float v) {
  v = dppmax<0xB1>(v);   // quad_perm swap xor1
  v = dppmax<0x4E>(v);   // quad_perm swap xor2
  v = dppmax<0x141>(v);  // row_half_mirror (pairs quads)
  v = dppmax<0x128>(v);  // row_ror:8 (pairs octs)
  return v;
}

// ---------- k_pack: weights -> MFMA A-frags (bf16) + packed m1 weights ----------
// frag f element (lane l, j) = W[(s*32 + (l>>4)*8 + j)][mt*16 + (l&15)]
//   f in [0,8):   m2  frags, f = mt*2 + s
//   f in [8,40):  m3a frags, f-8  = mt*4 + s
//   f in [40,72): m3b frags, f-40 = mt*4 + s
// at byte 73728: w14[64] float4 = {m1w_x, m1w_y, m1w_z, m1b} at swizzled pos
__global__ __launch_bounds__(256) void k_pack(const float* __restrict__ m2w,
                                              const float* __restrict__ m3aw,
                                              const float* __restrict__ m3bw,
                                              const float* __restrict__ m1w,
                                              const float* __restrict__ m1b,
                                              u16* __restrict__ pk) {
  int e = blockIdx.x * 256 + threadIdx.x;
  if (e < 72 * 512) {
    int f = e >> 9;
    int le = e & 511;
    int l = le >> 3, j = le & 7;
    int qq = l >> 4, mm = l & 15;
    float v;
    if (f < 8) {
      int mt = f >> 1, s = f & 1;
      v = m2w[(s * 32 + qq * 8 + j) * 64 + mt * 16 + mm];
    } else if (f < 40) {
      int ff = f - 8; int mt = ff >> 2, s = ff & 3;
      v = m3aw[(s * 32 + qq * 8 + j) * 128 + mt * 16 + mm];
    } else {
      int ff = f - 40; int mt = ff >> 2, s = ff & 3;
      v = m3bw[(s * 32 + qq * 8 + j) * 128 + mt * 16 + mm];
    }
    pk[e] = f2bf(v);
  }
  if (e < 64) {
    // c = s*32 + q*8 + j  ->  p = s*32 + j*4 + q  (bank-spread for per-lane float4 reads)
    int p = (e & 32) + (e & 7) * 4 + ((e >> 3) & 3);
    float4* w14 = (float4*)(pk + 36864);
    w14[p] = make_float4(m1w[e], m1w[64 + e], m1w[128 + e], m1b[e]);
  }
}

// ---------- k_proj: xp = x @ W, output bf16 pairs ----------
__global__ __launch_bounds__(256) void k_proj(const float* __restrict__ x,
                                              const float* __restrict__ W,
                                              u32* __restrict__ xp, int n) {
  __shared__ __align__(16) float Ws[CIN * COUT];
  int t = threadIdx.x;
  {
    const float4* W4 = (const float4*)W;
    float4* Ws4 = (float4*)Ws;
#pragma unroll
    for (int i = 0; i < 16; i++) Ws4[t + i * 256] = W4[t + i * 256];
  }
  __syncthreads();
  int gid = blockIdx.x * 256 + t;
  int r = gid >> 3;
  if (r >= n) return;
  int cb = (gid & 7) * 4;
  float acc[4][4];
#pragma unroll
  for (int g = 0; g < 4; g++)
#pragma unroll
    for (int j = 0; j < 4; j++) acc[g][j] = 0.f;
  const float4* xrow = (const float4*)(x + (size_t)r * CIN);
  for (int i4 = 0; i4 < CIN / 4; i4++) {
    float4 xv = xrow[i4];
    float xa[4] = {xv.x, xv.y, xv.z, xv.w};
#pragma unroll
    for (int j = 0; j < 4; j++) {
      float a = xa[j];
      int base = (i4 * 4 + j) * COUT + cb;
#pragma unroll
      for (int g = 0; g < 4; g++) {
        const float4 w = *(const float4*)&Ws[base + g * 32];
        acc[g][0] = fmaf(a, w.x, acc[g][0]);
        acc[g][1] = fmaf(a, w.y, acc[g][1]);
        acc[g][2] = fmaf(a, w.z, acc[g][2]);
        acc[g][3] = fmaf(a, w.w, acc[g][3]);
      }
    }
  }
  size_t rowb = (size_t)r * (COUT / 2);
#pragma unroll
  for (int g = 0; g < 4; g++) {
    int c = cb + g * 32;
    uint2 v;
    v.x = pack2(acc[g][0], acc[g][1]);
    v.y = pack2(acc[g][2], acc[g][3]);
    *(uint2*)&xp[rowb + (c >> 1)] = v;
  }
}

// ---------- k_lfa: MFMA fused NCA + gather + max ----------
// 8 waves/block, 2 points per wave iteration (frag loads shared across 2 MFMAs).
// m3a frags LDS-staged; m2/m3b frags from global (L1/L2-hot); sliced 1-KB
// scratch per point for the C->A layout round-trips; DPP-row-max epilogue.
__global__ __launch_bounds__(512, 4) void k_lfa(
    const float* __restrict__ xyz, const u32* __restrict__ xp,
    const int* __restrict__ knn, const u16* __restrict__ pk,
    const float* __restrict__ m2b, const float* __restrict__ m3ab,
    const float* __restrict__ m3bb, float* __restrict__ xsmax, int n) {
  __shared__ __align__(16) char fragA[32768];       // m3a frags
  __shared__ __align__(16) char scr[8][2][1280];    // per wave x point: 16 rows x 80 B

  const int t = threadIdx.x, wv = t >> 6, l = t & 63;
  const int q = l >> 4, m = l & 15;

  {  // stage m3a frags (pk bytes [8192, 40960))
    const uint4* src = (const uint4*)(pk + 4096);
    uint4* dst = (uint4*)fragA;
    for (int i = t; i < 2048; i += 512) dst[i] = src[i];
  }
  __syncthreads();

  const short8* pkf = (const short8*)pk;
  const float4* w14 = (const float4*)(pk + 36864);
  char* sA = scr[wv][0];
  char* sB = scr[wv][1];

  for (int pr = blockIdx.x * 8 + wv; pr * 2 < n; pr += gridDim.x * 8) {
    const int ptA = pr * 2;
    const int ptB = ptA + 1;
    const bool hasB = ptB < n;
    const int ptBc = hasB ? ptB : ptA;
    const int kidA = knn[(size_t)ptA * KNN + m];
    const int kidB = knn[(size_t)ptBc * KNN + m];
    float pxA = xyz[ptA * 3 + 0], pyA = xyz[ptA * 3 + 1], pzA = xyz[ptA * 3 + 2];
    float pxB = xyz[ptBc * 3 + 0], pyB = xyz[ptBc * 3 + 1], pzB = xyz[ptBc * 3 + 2];
    float axA = xyz[kidA * 3 + 0] - pxA, ayA = xyz[kidA * 3 + 1] - pyA, azA = xyz[kidA * 3 + 2] - pzA;
    float axB = xyz[kidB * 3 + 0] - pxB, ayB = xyz[kidB * 3 + 1] - pyB, azB = xyz[kidB * 3 + 2] - pzB;

    // p0 rows in B-frag layout (registers)
    float p0A[16], p0B[16];
#pragma unroll
    for (int s = 0; s < 2; s++)
#pragma unroll
      for (int j = 0; j < 8; j++) {
        float4 w = w14[s * 32 + j * 4 + q];
        p0A[s * 8 + j] = fmaf(axA, w.x, fmaf(ayA, w.y, fmaf(azA, w.z, w.w)));
        p0B[s * 8 + j] = fmaf(axB, w.x, fmaf(ayB, w.y, fmaf(azB, w.z, w.w)));
      }
    S8U bp0A[2], bp0B[2], bplA[2], bplB[2];
#pragma unroll
    for (int s = 0; s < 2; s++)
#pragma unroll
      for (int jj = 0; jj < 4; jj++) {
        bp0A[s].u[jj] = pack2(p0A[s * 8 + 2 * jj], p0A[s * 8 + 2 * jj + 1]);
        bp0B[s].u[jj] = pack2(p0B[s * 8 + 2 * jj], p0B[s * 8 + 2 * jj + 1]);
      }
    // p_local = max over k (= lanes 0..15 of the DPP row), in place
#pragma unroll
    for (int i = 0; i < 16; i++) { p0A[i] = rowmax16(p0A[i]); p0B[i] = rowmax16(p0B[i]); }
#pragma unroll
    for (int s = 0; s < 2; s++)
#pragma unroll
      for (int jj = 0; jj < 4; jj++) {
        bplA[s].u[jj] = pack2(p0A[s * 8 + 2 * jj], p0A[s * 8 + 2 * jj + 1]);
        bplB[s].u[jj] = pack2(p0B[s * 8 + 2 * jj], p0B[s * 8 + 2 * jj + 1]);
      }

    // ---- m2 -> p1 (sliced) -> bpf frags
    short8 bpfA[2], bpfB[2];
#pragma unroll
    for (int s = 0; s < 2; s++) {
#pragma unroll
      for (int h = 0; h < 2; h++) {
        int mt = 2 * s + h;
        float4 bb = *(const float4*)&m2b[mt * 16 + q * 4];
        f32x4 accA = {bb.x, bb.y, bb.z, bb.w};
        f32x4 accB = accA;
#pragma unroll
        for (int ks = 0; ks < 2; ks++) {
          short8 af = pkf[(mt * 2 + ks) * 64 + l];
          accA = MFMA16(af, bp0A[ks].s, accA);
          accB = MFMA16(af, bp0B[ks].s, accB);
        }
        uint2 wA; wA.x = pack2(accA[0], accA[1]); wA.y = pack2(accA[2], accA[3]);
        uint2 wB; wB.x = pack2(accB[0], accB[1]); wB.y = pack2(accB[2], accB[3]);
        *(uint2*)(sA + m * 80 + h * 32 + q * 8) = wA;
        *(uint2*)(sB + m * 80 + h * 32 + q * 8) = wB;
      }
      bpfA[s] = *(const short8*)(sA + m * 80 + q * 16);
      bpfB[s] = *(const short8*)(sB + m * 80 + q * 16);
    }

    // ---- m3a -> gelu -> g (sliced) -> bg frags
    short8 bgA[4], bgB[4];
#pragma unroll
    for (int s = 0; s < 4; s++) {
#pragma unroll
      for (int h = 0; h < 2; h++) {
        int mt = 2 * s + h;
        float4 bb = *(const float4*)&m3ab[mt * 16 + q * 4];
        f32x4 accA = {bb.x, bb.y, bb.z, bb.w};
        f32x4 accB = accA;
#pragma unroll
        for (int ks = 0; ks < 4; ks++) {
          short8 af = *(const short8*)(fragA + (mt * 4 + ks) * 1024 + l * 16);
          short8 bA = (ks == 0) ? bpfA[0] : (ks == 1) ? bpfA[1] : (ks == 2) ? bplA[0].s : bplA[1].s;
          short8 bB = (ks == 0) ? bpfB[0] : (ks == 1) ? bpfB[1] : (ks == 2) ? bplB[0].s : bplB[1].s;
          accA = MFMA16(af, bA, accA);
          accB = MFMA16(af, bB, accB);
        }
        uint2 wA; wA.x = pack2(gelu_fast(accA[0]), gelu_fast(accA[1]));
        wA.y = pack2(gelu_fast(accA[2]), gelu_fast(accA[3]));
        uint2 wB; wB.x = pack2(gelu_fast(accB[0]), gelu_fast(accB[1]));
        wB.y = pack2(gelu_fast(accB[2]), gelu_fast(accB[3]));
        *(uint2*)(sA + m * 80 + h * 32 + q * 8) = wA;
        *(uint2*)(sB + m * 80 + h * 32 + q * 8) = wB;
      }
      bgA[s] = *(const short8*)(sA + m * 80 + q * 16);
      bgB[s] = *(const short8*)(sB + m * 80 + q * 16);
    }

    // ---- m3b -> pe (sliced) -> gather + DPP-max epilogue
#pragma unroll
    for (int s = 0; s < 4; s++) {
#pragma unroll
      for (int h = 0; h < 2; h++) {
        int mt = 2 * s + h;
        float4 bb = *(const float4*)&m3bb[mt * 16 + q * 4];
        f32x4 accA = {bb.x, bb.y, bb.z, bb.w};
        f32x4 accB = accA;
#pragma unroll
        for (int ks = 0; ks < 4; ks++) {
          short8 af = pkf[(40 + mt * 4 + ks) * 64 + l];
          accA = MFMA16(af, bgA[ks], accA);
          accB = MFMA16(af, bgB[ks], accB);
        }
        uint2 wA; wA.x = pack2(accA[0], accA[1]); wA.y = pack2(accA[2], accA[3]);
        uint2 wB; wB.x = pack2(accB[0], accB[1]); wB.y = pack2(accB[2], accB[3]);
        *(uint2*)(sA + m * 80 + h * 32 + q * 8) = wA;
        *(uint2*)(sB + m * 80 + h * 32 + q * 8) = wB;
      }
      // epilogue slice s: channels 32s + q*8 + [0..7]; lane's k-row = m (kid pre-loaded)
      {
        uint4 gA = *(const uint4*)(xp + (size_t)kidA * 64 + s * 16 + q * 4);
        uint4 pA = *(const uint4*)(sA + m * 80 + q * 16);
        float v0 = bf_lo(gA.x) + bf_lo(pA.x), v1 = bf_hi(gA.x) + bf_hi(pA.x);
        float v2 = bf_lo(gA.y) + bf_lo(pA.y), v3 = bf_hi(gA.y) + bf_hi(pA.y);
        float v4 = bf_lo(gA.z) + bf_lo(pA.z), v5 = bf_hi(gA.z) + bf_hi(pA.z);
        float v6 = bf_lo(gA.w) + bf_lo(pA.w), v7 = bf_hi(gA.w) + bf_hi(pA.w);
        v0 = rowmax16(v0); v1 = rowmax16(v1); v2 = rowmax16(v2); v3 = rowmax16(v3);
        v4 = rowmax16(v4); v5 = rowmax16(v5); v6 = rowmax16(v6); v7 = rowmax16(v7);
        if (m == 0) {
          uint4 sf = *(const uint4*)(xp + (size_t)ptA * 64 + s * 16 + q * 4);
          float4 o1 = make_float4(v0 - bf_lo(sf.x), v1 - bf_hi(sf.x),
                                  v2 - bf_lo(sf.y), v3 - bf_hi(sf.y));
          float4 o2 = make_float4(v4 - bf_lo(sf.z), v5 - bf_hi(sf.z),
                                  v6 - bf_lo(sf.w), v7 - bf_hi(sf.w));
          *(float4*)&xsmax[(size_t)ptA * COUT + s * 32 + q * 8] = o1;
          *(float4*)&xsmax[(size_t)ptA * COUT + s * 32 + q * 8 + 4] = o2;
        }
        if (hasB) {
          uint4 gB = *(const uint4*)(xp + (size_t)kidB * 64 + s * 16 + q * 4);
          uint4 pB = *(const uint4*)(sB + m * 80 + q * 16);
          float w0 = bf_lo(gB.x) + bf_lo(pB.x), w1 = bf_hi(gB.x) + bf_hi(pB.x);
          float w2 = bf_lo(gB.y) + bf_lo(pB.y), w3 = bf_hi(gB.y) + bf_hi(pB.y);
          float w4 = bf_lo(gB.z) + bf_lo(pB.z), w5 = bf_hi(gB.z) + bf_hi(pB.z);
          float w6 = bf_lo(gB.w) + bf_lo(pB.w), w7 = bf_hi(gB.w) + bf_hi(pB.w);
          w0 = rowmax16(w0); w1 = rowmax16(w1); w2 = rowmax16(w2); w3 = rowmax16(w3);
          w4 = rowmax16(w4); w5 = rowmax16(w5); w6 = rowmax16(w6); w7 = rowmax16(w7);
          if (m == 0) {
            uint4 sf = *(const uint4*)(xp + (size_t)ptB * 64 + s * 16 + q * 4);
            float4 o1 = make_float4(w0 - bf_lo(sf.x), w1 - bf_hi(sf.x),
                                    w2 - bf_lo(sf.y), w3 - bf_hi(sf.y));
            float4 o2 = make_float4(w4 - bf_lo(sf.z), w5 - bf_hi(sf.z),
                                    w6 - bf_lo(sf.w), w7 - bf_hi(sf.w));
            *(float4*)&xsmax[(size_t)ptB * COUT + s * 32 + q * 8] = o1;
            *(float4*)&xsmax[(size_t)ptB * COUT + s * 32 + q * 8 + 4] = o2;
          }
        }
      }
    }
  }
}

// ---------- BN stats ----------
__global__ __launch_bounds__(256) void k_bnstats(const float* __restrict__ xs,
                                                 float* __restrict__ sums, int n) {
  int t = threadIdx.x;
  int c = t & 127;
  int h = t >> 7;
  float s = 0.f, s2 = 0.f;
  for (int r = blockIdx.x * 2 + h; r < n; r += gridDim.x * 2) {
    float v = xs[(size_t)r * COUT + c];
    s += v;
    s2 += v * v;
  }
  __shared__ float red[256];
  red[t] = s;
  __syncthreads();
  if (h == 0) atomicAdd(&sums[c], s + red[t + 128]);
  __syncthreads();
  red[t] = s2;
  __syncthreads();
  if (h == 0) atomicAdd(&sums[128 + c], s2 + red[t + 128]);
}

// ---------- BN normalize ----------
__global__ __launch_bounds__(256) void k_bnnorm(const float* __restrict__ xs,
                                                const float* __restrict__ sums,
                                                const float* __restrict__ gamma,
                                                const float* __restrict__ beta,
                                                float* __restrict__ out, int n) {
  size_t i = (size_t)blockIdx.x * 256 + threadIdx.x;
  size_t total4 = (size_t)n * (COUT / 4);
  if (i >= total4) return;
  int c = (int)((i * 4) & (COUT - 1));
  float4 v = ((const float4*)xs)[i];
  float4 sm = *(const float4*)&sums[c];
  float4 sq = *(const float4*)&sums[128 + c];
  float4 gm = *(const float4*)&gamma[c];
  float4 bt = *(const float4*)&beta[c];
  float inv_n = 1.0f / (float)n;
  float4 o;
  { float mean = sm.x * inv_n, var = sq.x * inv_n - mean * mean;
    o.x = (v.x - mean) * rsqrtf(var + EPS) * gm.x + bt.x; }
  { float mean = sm.y * inv_n, var = sq.y * inv_n - mean * mean;
    o.y = (v.y - mean) * rsqrtf(var + EPS) * gm.y + bt.y; }
  { float mean = sm.z * inv_n, var = sq.z * inv_n - mean * mean;
    o.z = (v.z - mean) * rsqrtf(var + EPS) * gm.z + bt.z; }
  { float mean = sm.w * inv_n, var = sq.w * inv_n - mean * mean;
    o.w = (v.w - mean) * rsqrtf(var + EPS) * gm.w + bt.w; }
  ((float4*)out)[i] = o;
}

// ---------- launch ----------
extern "C" void kernel_launch(void* const* d_in, const int* in_sizes, int n_in,
                              void* d_out, int out_size, void* d_ws, size_t ws_size,
                              hipStream_t stream) {
  const float* xyz = (const float*)d_in[0];
  const float* x = (const float*)d_in[1];
  const int* knn = (const int*)d_in[2];
  const float* W = (const float*)d_in[3];
  const float* m1w = (const float*)d_in[4];
  const float* m1b = (const float*)d_in[5];
  const float* m2w = (const float*)d_in[6];
  const float* m3aw = (const float*)d_in[8];
  const float* m3bw = (const float*)d_in[10];
  const float* m2b = (const float*)d_in[7];
  const float* m3ab = (const float*)d_in[9];
  const float* m3bb = (const float*)d_in[11];
  const float* gamma = (const float*)d_in[12];
  const float* beta = (const float*)d_in[13];
  float* out = (float*)d_out;

  int n = in_sizes[0] / 3;

  char* ws = (char*)d_ws;
  u16* pk = (u16*)ws;                       // 72 KB frags + 1 KB w14 = 74752 B
  size_t o1 = 74752;
  u32* xp = (u32*)(ws + o1);                // n * 256 B
  size_t o2 = o1 + (((size_t)n * 256 + 255) & ~(size_t)255);
  float* xsm = (float*)(ws + o2);           // n * 512 B
  size_t o3 = o2 + (((size_t)n * 512 + 255) & ~(size_t)255);
  float* sums = (float*)(ws + o3);          // 256 floats

  hipMemsetAsync(sums, 0, 256 * sizeof(float), stream);
  k_pack<<<144, 256, 0, stream>>>(m2w, m3aw, m3bw, m1w, m1b, pk);
  k_proj<<<(n * 8 + 255) / 256, 256, 0, stream>>>(x, W, xp, n);
  k_lfa<<<512, 512, 0, stream>>>(xyz, xp, knn, pk, m2b, m3ab, m3bb, xsm, n);
  k_bnstats<<<512, 256, 0, stream>>>(xsm, sums, n);
  k_bnnorm<<<(int)(((size_t)n * (COUT / 4) + 255) / 256), 256, 0, stream>>>(
      xsm, sums, gamma, beta, out, n);
}

// Round 4
// 654.022 us; speedup vs baseline: 2.8537x; 1.6714x over previous
//
#include <hip/hip_runtime.h>
#include <hip/hip_bf16.h>
#include <math.h>

#define KNN 16
#define CIN 128
#define COUT 128
#define D2 64
#define EPS 1e-5f

typedef __attribute__((ext_vector_type(8))) short short8;
typedef __attribute__((ext_vector_type(4))) float f32x4;
typedef unsigned int u32;
typedef unsigned short u16;

union S8U { short8 s; u32 u[4]; };

#define MFMA16(a, b, c) __builtin_amdgcn_mfma_f32_16x16x32_bf16((a), (b), (c), 0, 0, 0)

static __device__ __forceinline__ u16 f2bf(float f) {
  __hip_bfloat16 h = __float2bfloat16(f);
  u16 u; __builtin_memcpy(&u, &h, 2); return u;
}
#if __has_builtin(__builtin_amdgcn_cvt_pk_bf16_f32)
static __device__ __forceinline__ u32 pack2(float a, float b) {
  auto r = __builtin_amdgcn_cvt_pk_bf16_f32(a, b);  // v_cvt_pk_bf16_f32 (gfx950)
  u32 u; __builtin_memcpy(&u, &r, 4); return u;
}
#else
static __device__ __forceinline__ u32 pack2(float a, float b) {
  return (u32)f2bf(a) | ((u32)f2bf(b) << 16);
}
#endif
static __device__ __forceinline__ float bf_lo(u32 u) { return __uint_as_float(u << 16); }
static __device__ __forceinline__ float bf_hi(u32 u) { return __uint_as_float(u & 0xffff0000u); }

// tanh-form gelu: gelu(x) ~= x * sigmoid(1.5957691*(x + 0.044715x^3)), max err ~1e-3
static __device__ __forceinline__ float gelu_fast(float x) {
  float x2 = x * x;
  float xs = x * -2.302118131f;              // -1.5957691*log2(e)*x
  float u = x2 * 0.044715f;
  float z = fmaf(u, xs, xs);                 // -a*log2e*(x + c x^3)
  float e = __builtin_amdgcn_exp2f(z);
  return x * __builtin_amdgcn_rcpf(1.0f + e);
}

// max-reduce over the 16-lane DPP row (lanes l..l|15)
template <int CTRL>
static __device__ __forceinline__ float dppmax(float v) {
  int s = __builtin_bit_cast(int, v);
  int t = __builtin_amdgcn_update_dpp(s, s, CTRL, 0xf, 0xf, true);
  return fmaxf(v, __builtin_bit_cast(float, t));
}
static __device__ __forceinline__ float rowmax16(float v) {
  v = dppmax<0xB1>(v);   // quad_perm xor1
  v = dppmax<0x4E>(v);   // quad_perm xor2
  v = dppmax<0x141>(v);  // row_half_mirror
  v = dppmax<0x128>(v);  // row_ror:8
  return v;
}

// ---------- k_pack: weights -> MFMA A-frags (bf16) + w14 + biases ----------
// pk byte layout: [0,73728) 72 frags (1 KB each: m2 f0..7, m3a f8..39, m3b f40..71)
//                 [73728,74752) w14 float4[64] (m1w xyz + m1b, swizzled)
//                 [74752,76032) biases float[320]: m2b@0, m3ab@64, m3bb@192
__global__ __launch_bounds__(256) void k_pack(const float* __restrict__ m2w,
                                              const float* __restrict__ m3aw,
                                              const float* __restrict__ m3bw,
                                              const float* __restrict__ m1w,
                                              const float* __restrict__ m1b,
                                              const float* __restrict__ m2b,
                                              const float* __restrict__ m3ab,
                                              const float* __restrict__ m3bb,
                                              u16* __restrict__ pk) {
  int e = blockIdx.x * 256 + threadIdx.x;
  if (e < 72 * 512) {
    int f = e >> 9;
    int le = e & 511;
    int l = le >> 3, j = le & 7;
    int qq = l >> 4, mm = l & 15;
    float v;
    if (f < 8) {
      int mt = f >> 1, s = f & 1;
      v = m2w[(s * 32 + qq * 8 + j) * 64 + mt * 16 + mm];
    } else if (f < 40) {
      int ff = f - 8; int mt = ff >> 2, s = ff & 3;
      v = m3aw[(s * 32 + qq * 8 + j) * 128 + mt * 16 + mm];
    } else {
      int ff = f - 40; int mt = ff >> 2, s = ff & 3;
      v = m3bw[(s * 32 + qq * 8 + j) * 128 + mt * 16 + mm];
    }
    pk[e] = f2bf(v);
  }
  if (e < 64) {
    int p = (e & 32) + (e & 7) * 4 + ((e >> 3) & 3);
    float4* w14 = (float4*)(pk + 36864);
    w14[p] = make_float4(m1w[e], m1w[64 + e], m1w[128 + e], m1b[e]);
  }
  if (e < 320) {
    float* bias = (float*)(pk + 37376);
    bias[e] = (e < 64) ? m2b[e] : (e < 192) ? m3ab[e - 64] : m3bb[e - 192];
  }
}

// ---------- k_proj: xp = x @ W, output bf16 pairs ----------
__global__ __launch_bounds__(256) void k_proj(const float* __restrict__ x,
                                              const float* __restrict__ W,
                                              u32* __restrict__ xp, int n) {
  __shared__ __align__(16) float Ws[CIN * COUT];
  int t = threadIdx.x;
  {
    const float4* W4 = (const float4*)W;
    float4* Ws4 = (float4*)Ws;
#pragma unroll
    for (int i = 0; i < 16; i++) Ws4[t + i * 256] = W4[t + i * 256];
  }
  __syncthreads();
  int gid = blockIdx.x * 256 + t;
  int r = gid >> 3;
  if (r >= n) return;
  int cb = (gid & 7) * 4;
  float acc[4][4];
#pragma unroll
  for (int g = 0; g < 4; g++)
#pragma unroll
    for (int j = 0; j < 4; j++) acc[g][j] = 0.f;
  const float4* xrow = (const float4*)(x + (size_t)r * CIN);
  for (int i4 = 0; i4 < CIN / 4; i4++) {
    float4 xv = xrow[i4];
    float xa[4] = {xv.x, xv.y, xv.z, xv.w};
#pragma unroll
    for (int j = 0; j < 4; j++) {
      float a = xa[j];
      int base = (i4 * 4 + j) * COUT + cb;
#pragma unroll
      for (int g = 0; g < 4; g++) {
        const float4 w = *(const float4*)&Ws[base + g * 32];
        acc[g][0] = fmaf(a, w.x, acc[g][0]);
        acc[g][1] = fmaf(a, w.y, acc[g][1]);
        acc[g][2] = fmaf(a, w.z, acc[g][2]);
        acc[g][3] = fmaf(a, w.w, acc[g][3]);
      }
    }
  }
  size_t rowb = (size_t)r * (COUT / 2);
#pragma unroll
  for (int g = 0; g < 4; g++) {
    int c = cb + g * 32;
    uint2 v;
    v.x = pack2(acc[g][0], acc[g][1]);
    v.y = pack2(acc[g][2], acc[g][3]);
    *(uint2*)&xp[rowb + (c >> 1)] = v;
  }
}

// ---------- k_lfa: MFMA fused NCA + gather + max ----------
// 16 waves/block (1024 thr), 1 block/CU (LDS 117 KB), 2 points per wave iter.
// ALL weight frags + w14 + biases in LDS (L2 is thrashed by the gather stream).
// m3b epilogue fused: pe stays in regs; gather uint2 per tile; DPP rowmax; store.
__global__ __launch_bounds__(1024, 4) void k_lfa(
    const float* __restrict__ xyz, const u32* __restrict__ xp,
    const int* __restrict__ knn, const u16* __restrict__ pk,
    float* __restrict__ xsmax, int n) {
  __shared__ __align__(16) char lds[76032 + 16 * 2 * 1280];  // 116992 B

  const int t = threadIdx.x, wv = t >> 6, l = t & 63;
  const int q = l >> 4, m = l & 15;

  {  // stage frags + w14 + biases (76032 B = 4752 uint4)
    const uint4* src = (const uint4*)pk;
    uint4* dst = (uint4*)lds;
    for (int i = t; i < 4752; i += 1024) dst[i] = src[i];
  }
  __syncthreads();

  const char* fr = lds;
  const float4* w14 = (const float4*)(lds + 73728);
  const float* bias = (const float*)(lds + 74752);   // m2b@0, m3ab@64, m3bb@192
  char* sA = lds + 76032 + wv * 2560;
  char* sB = sA + 1280;

  for (int pr = blockIdx.x * 16 + wv; pr * 2 < n; pr += gridDim.x * 16) {
    const int ptA = pr * 2;
    const int ptB = ptA + 1;
    const bool hasB = ptB < n;
    const int ptBc = hasB ? ptB : ptA;
    const int kidA = knn[(size_t)ptA * KNN + m];
    const int kidB = knn[(size_t)ptBc * KNN + m];
    float pxA = xyz[ptA * 3 + 0], pyA = xyz[ptA * 3 + 1], pzA = xyz[ptA * 3 + 2];
    float pxB = xyz[ptBc * 3 + 0], pyB = xyz[ptBc * 3 + 1], pzB = xyz[ptBc * 3 + 2];
    float axA = xyz[kidA * 3 + 0] - pxA, ayA = xyz[kidA * 3 + 1] - pyA, azA = xyz[kidA * 3 + 2] - pzA;
    float axB = xyz[kidB * 3 + 0] - pxB, ayB = xyz[kidB * 3 + 1] - pyB, azB = xyz[kidB * 3 + 2] - pzB;

    // ---- p0 rows in B-frag layout (registers)
    float p0A[16], p0B[16];
#pragma unroll
    for (int s = 0; s < 2; s++)
#pragma unroll
      for (int j = 0; j < 8; j++) {
        float4 w = w14[s * 32 + j * 4 + q];
        p0A[s * 8 + j] = fmaf(axA, w.x, fmaf(ayA, w.y, fmaf(azA, w.z, w.w)));
        p0B[s * 8 + j] = fmaf(axB, w.x, fmaf(ayB, w.y, fmaf(azB, w.z, w.w)));
      }
    S8U bp0A[2], bp0B[2], bplA[2], bplB[2];
#pragma unroll
    for (int s = 0; s < 2; s++)
#pragma unroll
      for (int jj = 0; jj < 4; jj++) {
        bp0A[s].u[jj] = pack2(p0A[s * 8 + 2 * jj], p0A[s * 8 + 2 * jj + 1]);
        bp0B[s].u[jj] = pack2(p0B[s * 8 + 2 * jj], p0B[s * 8 + 2 * jj + 1]);
      }
#pragma unroll
    for (int i = 0; i < 16; i++) { p0A[i] = rowmax16(p0A[i]); p0B[i] = rowmax16(p0B[i]); }
#pragma unroll
    for (int s = 0; s < 2; s++)
#pragma unroll
      for (int jj = 0; jj < 4; jj++) {
        bplA[s].u[jj] = pack2(p0A[s * 8 + 2 * jj], p0A[s * 8 + 2 * jj + 1]);
        bplB[s].u[jj] = pack2(p0B[s * 8 + 2 * jj], p0B[s * 8 + 2 * jj + 1]);
      }

    // ---- m2 -> p1 (sliced scratch) -> bpf frags
    short8 bpfA[2], bpfB[2];
#pragma unroll
    for (int s = 0; s < 2; s++) {
#pragma unroll
      for (int h = 0; h < 2; h++) {
        int mt = 2 * s + h;
        float4 bb = *(const float4*)&bias[mt * 16 + q * 4];
        f32x4 accA = {bb.x, bb.y, bb.z, bb.w};
        f32x4 accB = accA;
#pragma unroll
        for (int ks = 0; ks < 2; ks++) {
          short8 af = *(const short8*)(fr + (mt * 2 + ks) * 1024 + l * 16);
          accA = MFMA16(af, bp0A[ks].s, accA);
          accB = MFMA16(af, bp0B[ks].s, accB);
        }
        uint2 wA; wA.x = pack2(accA[0], accA[1]); wA.y = pack2(accA[2], accA[3]);
        uint2 wB; wB.x = pack2(accB[0], accB[1]); wB.y = pack2(accB[2], accB[3]);
        *(uint2*)(sA + m * 80 + h * 32 + q * 8) = wA;
        *(uint2*)(sB + m * 80 + h * 32 + q * 8) = wB;
      }
      bpfA[s] = *(const short8*)(sA + m * 80 + q * 16);
      bpfB[s] = *(const short8*)(sB + m * 80 + q * 16);
    }

    // ---- m3a -> gelu -> g (sliced scratch) -> bg frags
    short8 bgA[4], bgB[4];
#pragma unroll
    for (int s = 0; s < 4; s++) {
#pragma unroll
      for (int h = 0; h < 2; h++) {
        int mt = 2 * s + h;
        float4 bb = *(const float4*)&bias[64 + mt * 16 + q * 4];
        f32x4 accA = {bb.x, bb.y, bb.z, bb.w};
        f32x4 accB = accA;
#pragma unroll
        for (int ks = 0; ks < 4; ks++) {
          short8 af = *(const short8*)(fr + (8 + mt * 4 + ks) * 1024 + l * 16);
          short8 bA = (ks == 0) ? bpfA[0] : (ks == 1) ? bpfA[1] : (ks == 2) ? bplA[0].s : bplA[1].s;
          short8 bB = (ks == 0) ? bpfB[0] : (ks == 1) ? bpfB[1] : (ks == 2) ? bplB[0].s : bplB[1].s;
          accA = MFMA16(af, bA, accA);
          accB = MFMA16(af, bB, accB);
        }
        uint2 wA; wA.x = pack2(gelu_fast(accA[0]), gelu_fast(accA[1]));
        wA.y = pack2(gelu_fast(accA[2]), gelu_fast(accA[3]));
        uint2 wB; wB.x = pack2(gelu_fast(accB[0]), gelu_fast(accB[1]));
        wB.y = pack2(gelu_fast(accB[2]), gelu_fast(accB[3]));
        *(uint2*)(sA + m * 80 + h * 32 + q * 8) = wA;
        *(uint2*)(sB + m * 80 + h * 32 + q * 8) = wB;
      }
      bgA[s] = *(const short8*)(sA + m * 80 + q * 16);
      bgB[s] = *(const short8*)(sB + m * 80 + q * 16);
    }

    // ---- m3b + fused epilogue (pe in regs; lane's k-row = m, kid preloaded)
#pragma unroll
    for (int mt = 0; mt < 8; mt++) {
      float4 bb = *(const float4*)&bias[192 + mt * 16 + q * 4];
      f32x4 accA = {bb.x, bb.y, bb.z, bb.w};
      f32x4 accB = accA;
#pragma unroll
      for (int ks = 0; ks < 4; ks++) {
        short8 af = *(const short8*)(fr + (40 + mt * 4 + ks) * 1024 + l * 16);
        accA = MFMA16(af, bgA[ks], accA);
        accB = MFMA16(af, bgB[ks], accB);
      }
      {
        uint2 ga = *(const uint2*)(xp + (size_t)kidA * 64 + mt * 8 + q * 2);
        float v0 = bf_lo(ga.x) + accA[0];
        float v1 = bf_hi(ga.x) + accA[1];
        float v2 = bf_lo(ga.y) + accA[2];
        float v3 = bf_hi(ga.y) + accA[3];
        v0 = rowmax16(v0); v1 = rowmax16(v1); v2 = rowmax16(v2); v3 = rowmax16(v3);
        if (m == 0) {
          uint2 sf = *(const uint2*)(xp + (size_t)ptA * 64 + mt * 8 + q * 2);
          float4 o = make_float4(v0 - bf_lo(sf.x), v1 - bf_hi(sf.x),
                                 v2 - bf_lo(sf.y), v3 - bf_hi(sf.y));
          *(float4*)&xsmax[(size_t)ptA * COUT + mt * 16 + q * 4] = o;
        }
      }
      if (hasB) {
        uint2 gb = *(const uint2*)(xp + (size_t)kidB * 64 + mt * 8 + q * 2);
        float v0 = bf_lo(gb.x) + accB[0];
        float v1 = bf_hi(gb.x) + accB[1];
        float v2 = bf_lo(gb.y) + accB[2];
        float v3 = bf_hi(gb.y) + accB[3];
        v0 = rowmax16(v0); v1 = rowmax16(v1); v2 = rowmax16(v2); v3 = rowmax16(v3);
        if (m == 0) {
          uint2 sf = *(const uint2*)(xp + (size_t)ptB * 64 + mt * 8 + q * 2);
          float4 o = make_float4(v0 - bf_lo(sf.x), v1 - bf_hi(sf.x),
                                 v2 - bf_lo(sf.y), v3 - bf_hi(sf.y));
          *(float4*)&xsmax[(size_t)ptB * COUT + mt * 16 + q * 4] = o;
        }
      }
    }
  }
}

// ---------- BN stage 1: per-block partial sums ----------
__global__ __launch_bounds__(256) void k_bnstats(const float* __restrict__ xs,
                                                 float* __restrict__ part, int n) {
  int t = threadIdx.x;
  int c = t & 127;
  int h = t >> 7;
  float s = 0.f, s2 = 0.f;
  for (int r = blockIdx.x * 2 + h; r < n; r += gridDim.x * 2) {
    float v = xs[(size_t)r * COUT + c];
    s += v;
    s2 += v * v;
  }
  __shared__ float red[256];
  red[t] = s;
  __syncthreads();
  if (h == 0) part[blockIdx.x * 256 + c] = s + red[t + 128];
  __syncthreads();
  red[t] = s2;
  __syncthreads();
  if (h == 0) part[blockIdx.x * 256 + 128 + c] = s2 + red[t + 128];
}

// ---------- BN stage 2: finalize mean/invstd ----------
__global__ void k_bnfinal(const float* __restrict__ part, float* __restrict__ ms,
                          int n, int nb) {
  int c = threadIdx.x;  // 128 threads
  float s = 0.f, s2 = 0.f;
  for (int b = 0; b < nb; b++) {
    s += part[b * 256 + c];
    s2 += part[b * 256 + 128 + c];
  }
  float inv_n = 1.0f / (float)n;
  float mean = s * inv_n;
  float var = s2 * inv_n - mean * mean;
  ms[c] = mean;
  ms[128 + c] = rsqrtf(var + EPS);
}

// ---------- BN normalize ----------
__global__ __launch_bounds__(256) void k_bnnorm(const float* __restrict__ xs,
                                                const float* __restrict__ ms,
                                                const float* __restrict__ gamma,
                                                const float* __restrict__ beta,
                                                float* __restrict__ out, int n) {
  size_t i = (size_t)blockIdx.x * 256 + threadIdx.x;
  size_t total4 = (size_t)n * (COUT / 4);
  if (i >= total4) return;
  int c = (int)((i * 4) & (COUT - 1));
  float4 v = ((const float4*)xs)[i];
  float4 mn = *(const float4*)&ms[c];
  float4 iv = *(const float4*)&ms[128 + c];
  float4 gm = *(const float4*)&gamma[c];
  float4 bt = *(const float4*)&beta[c];
  float4 o;
  o.x = (v.x - mn.x) * iv.x * gm.x + bt.x;
  o.y = (v.y - mn.y) * iv.y * gm.y + bt.y;
  o.z = (v.z - mn.z) * iv.z * gm.z + bt.z;
  o.w = (v.w - mn.w) * iv.w * gm.w + bt.w;
  ((float4*)out)[i] = o;
}

// ---------- launch ----------
extern "C" void kernel_launch(void* const* d_in, const int* in_sizes, int n_in,
                              void* d_out, int out_size, void* d_ws, size_t ws_size,
                              hipStream_t stream) {
  const float* xyz = (const float*)d_in[0];
  const float* x = (const float*)d_in[1];
  const int* knn = (const int*)d_in[2];
  const float* W = (const float*)d_in[3];
  const float* m1w = (const float*)d_in[4];
  const float* m1b = (const float*)d_in[5];
  const float* m2w = (const float*)d_in[6];
  const float* m2b = (const float*)d_in[7];
  const float* m3aw = (const float*)d_in[8];
  const float* m3ab = (const float*)d_in[9];
  const float* m3bw = (const float*)d_in[10];
  const float* m3bb = (const float*)d_in[11];
  const float* gamma = (const float*)d_in[12];
  const float* beta = (const float*)d_in[13];
  float* out = (float*)d_out;

  int n = in_sizes[0] / 3;

  char* ws = (char*)d_ws;
  u16* pk = (u16*)ws;                       // 76032 B (frags + w14 + biases)
  size_t o1 = 76288;
  u32* xp = (u32*)(ws + o1);                // n * 256 B
  size_t o2 = o1 + (((size_t)n * 256 + 255) & ~(size_t)255);
  float* xsm = (float*)(ws + o2);           // n * 512 B
  size_t o3 = o2 + (((size_t)n * 512 + 255) & ~(size_t)255);
  float* part = (float*)(ws + o3);          // 256 blocks * 256 floats = 256 KB
  size_t o4 = o3 + 262144;
  float* ms = (float*)(ws + o4);            // 256 floats (mean | invstd)

  k_pack<<<144, 256, 0, stream>>>(m2w, m3aw, m3bw, m1w, m1b, m2b, m3ab, m3bb, pk);
  k_proj<<<(n * 8 + 255) / 256, 256, 0, stream>>>(x, W, xp, n);
  k_lfa<<<256, 1024, 0, stream>>>(xyz, xp, knn, pk, xsm, n);
  k_bnstats<<<256, 256, 0, stream>>>(xsm, part, n);
  k_bnfinal<<<1, 128, 0, stream>>>(part, ms, n, 256);
  k_bnnorm<<<(int)(((size_t)n * (COUT / 4) + 255) / 256), 256, 0, stream>>>(
      xsm, ms, gamma, beta, out, n);
}

// Round 5
// 614.705 us; speedup vs baseline: 3.0362x; 1.0640x over previous
//
#include <hip/hip_runtime.h>
#include <hip/hip_bf16.h>
#include <math.h>

#define KNN 16
#define CIN 128
#define COUT 128
#define D2 64
#define EPS 1e-5f

typedef __attribute__((ext_vector_type(8))) short short8;
typedef __attribute__((ext_vector_type(4))) float f32x4;
typedef unsigned int u32;
typedef unsigned short u16;

union S8U { short8 s; u32 u[4]; };

#define MFMA16(a, b, c) __builtin_amdgcn_mfma_f32_16x16x32_bf16((a), (b), (c), 0, 0, 0)

static __device__ __forceinline__ u16 f2bf(float f) {
  __hip_bfloat16 h = __float2bfloat16(f);
  u16 u; __builtin_memcpy(&u, &h, 2); return u;
}
#if __has_builtin(__builtin_amdgcn_cvt_pk_bf16_f32)
static __device__ __forceinline__ u32 pack2(float a, float b) {
  auto r = __builtin_amdgcn_cvt_pk_bf16_f32(a, b);  // v_cvt_pk_bf16_f32 (gfx950)
  u32 u; __builtin_memcpy(&u, &r, 4); return u;
}
#else
static __device__ __forceinline__ u32 pack2(float a, float b) {
  return (u32)f2bf(a) | ((u32)f2bf(b) << 16);
}
#endif
static __device__ __forceinline__ float bf_lo(u32 u) { return __uint_as_float(u << 16); }
static __device__ __forceinline__ float bf_hi(u32 u) { return __uint_as_float(u & 0xffff0000u); }

// gelu(x) ~= x * sigmoid(1.702 x); 1.702*log2(e) = 2.4555331
static __device__ __forceinline__ float gelu_fast(float x) {
  float e = __builtin_amdgcn_exp2f(x * -2.4555331f);
  return x * __builtin_amdgcn_rcpf(1.0f + e);
}

// max-reduce over the 16-lane DPP row (lanes l..l|15)
template <int CTRL>
static __device__ __forceinline__ float dppmax(float v) {
  int s = __builtin_bit_cast(int, v);
  int t = __builtin_amdgcn_update_dpp(s, s, CTRL, 0xf, 0xf, true);
  return fmaxf(v, __builtin_bit_cast(float, t));
}
static __device__ __forceinline__ float rowmax16(float v) {
  v = dppmax<0xB1>(v);   // quad_perm xor1
  v = dppmax<0x4E>(v);   // quad_perm xor2
  v = dppmax<0x141>(v);  // row_half_mirror
  v = dppmax<0x128>(v);  // row_ror:8
  return v;
}

// ---------- k_proj: xp = x @ W via MFMA (xp^T tiles), bf16-pair output ----------
// A = W^T frags (LDS, packed per block), B = x-row frags (registers).
// C-layout: lane (q,m) -> point m of the 16-row tile, channels mt*16+q*4+r.
__global__ __launch_bounds__(256) void k_proj(const float* __restrict__ x,
                                              const float* __restrict__ W,
                                              u32* __restrict__ xp, int n) {
  __shared__ __align__(16) u32 Wf[8192];  // 32 frags (8 mt x 4 ks) x 256 u32
  const int t = threadIdx.x;
  for (int idx = t; idx < 8192; idx += 256) {
    int f = idx >> 8, rem = idx & 255;
    int l = rem >> 2, jp = rem & 3;
    int mt = f >> 2, ks = f & 3;
    int qq = l >> 4, mm = l & 15;
    int k = ks * 32 + qq * 8 + jp * 2;
    int c = mt * 16 + mm;
    Wf[idx] = pack2(W[(size_t)k * COUT + c], W[(size_t)(k + 1) * COUT + c]);
  }
  __syncthreads();

  const int wv = t >> 6, l = t & 63;
  const int q = l >> 4, m = l & 15;
  const short8* Wf8 = (const short8*)Wf;

  for (int tile = blockIdx.x * 4 + wv; tile * 16 < n; tile += gridDim.x * 4) {
    int r0 = tile * 16;
    int rr = min(r0 + m, n - 1);
    const float4* xr = (const float4*)(x + (size_t)rr * CIN);
    S8U xf[4];
#pragma unroll
    for (int ks = 0; ks < 4; ks++) {
      float4 a = xr[ks * 8 + q * 2];
      float4 b = xr[ks * 8 + q * 2 + 1];
      xf[ks].u[0] = pack2(a.x, a.y);
      xf[ks].u[1] = pack2(a.z, a.w);
      xf[ks].u[2] = pack2(b.x, b.y);
      xf[ks].u[3] = pack2(b.z, b.w);
    }
    bool ok = (r0 + m) < n;
    size_t rowb = (size_t)(r0 + m) * 64;
#pragma unroll
    for (int mt = 0; mt < 8; mt++) {
      f32x4 acc = {0.f, 0.f, 0.f, 0.f};
#pragma unroll
      for (int ks = 0; ks < 4; ks++)
        acc = MFMA16(Wf8[(mt * 4 + ks) * 64 + l], xf[ks].s, acc);
      if (ok) {
        uint2 v;
        v.x = pack2(acc[0], acc[1]);
        v.y = pack2(acc[2], acc[3]);
        *(uint2*)&xp[rowb + mt * 8 + q * 2] = v;
      }
    }
  }
}

// ---------- k_lfa: MFMA fused NCA + gather + max ----------
// 16 waves/block, 1 block/CU (LDS 117 KB), 2 points per wave iteration.
// Each block packs ALL weights (m2/m3a/m3b frags + m1 + biases) from the raw
// global arrays into its own LDS (no k_pack kernel, no global pk buffer).
__global__ __launch_bounds__(1024, 4) void k_lfa(
    const float* __restrict__ xyz, const u32* __restrict__ xp,
    const int* __restrict__ knn,
    const float* __restrict__ m1w, const float* __restrict__ m1b,
    const float* __restrict__ m2w, const float* __restrict__ m2b,
    const float* __restrict__ m3aw, const float* __restrict__ m3ab,
    const float* __restrict__ m3bw, const float* __restrict__ m3bb,
    float* __restrict__ xsmax, int n) {
  // [0,73728) frags (m2 f0..7, m3a f8..39, m3b f40..71), [73728,74752) w14,
  // [74752,76032) biases, [76032,116992) per-wave scratch 16 x 2560 B
  __shared__ __align__(16) char lds[116992];

  const int t = threadIdx.x, wv = t >> 6, l = t & 63;
  const int q = l >> 4, m = l & 15;

  {  // ---- per-block weight pack
    u32* lds32 = (u32*)lds;
    for (int idx = t; idx < 18432; idx += 1024) {
      int f = idx >> 8, rem = idx & 255;
      int ll = rem >> 2, jp = rem & 3;
      int qq = ll >> 4, mm = ll & 15;
      int j0 = jp * 2;
      float a, b;
      if (f < 8) {
        int mt = f >> 1, s = f & 1;
        const float* p = m2w + (size_t)(s * 32 + qq * 8 + j0) * D2 + mt * 16 + mm;
        a = p[0]; b = p[D2];
      } else if (f < 40) {
        int ff = f - 8; int mt = ff >> 2, s = ff & 3;
        const float* p = m3aw + (size_t)(s * 32 + qq * 8 + j0) * COUT + mt * 16 + mm;
        a = p[0]; b = p[COUT];
      } else {
        int ff = f - 40; int mt = ff >> 2, s = ff & 3;
        const float* p = m3bw + (size_t)(s * 32 + qq * 8 + j0) * COUT + mt * 16 + mm;
        a = p[0]; b = p[COUT];
      }
      lds32[idx] = pack2(a, b);
    }
    if (t < 64) {
      int p = (t & 32) + (t & 7) * 4 + ((t >> 3) & 3);
      ((float4*)(lds + 73728))[p] = make_float4(m1w[t], m1w[64 + t], m1w[128 + t], m1b[t]);
    }
    if (t < 320) {
      float* bias = (float*)(lds + 74752);
      bias[t] = (t < 64) ? m2b[t] : (t < 192) ? m3ab[t - 64] : m3bb[t - 192];
    }
  }
  __syncthreads();

  const char* fr = lds;
  const float4* w14 = (const float4*)(lds + 73728);
  const float* bias = (const float*)(lds + 74752);
  char* sA = lds + 76032 + wv * 2560;
  char* sB = sA + 1280;

  for (int pr = blockIdx.x * 16 + wv; pr * 2 < n; pr += gridDim.x * 16) {
    const int ptA = pr * 2;
    const int ptB = ptA + 1;
    const bool hasB = ptB < n;
    const int ptBc = hasB ? ptB : ptA;
    const int kidA = knn[(size_t)ptA * KNN + m];
    const int kidB = knn[(size_t)ptBc * KNN + m];
    float pxA = xyz[ptA * 3 + 0], pyA = xyz[ptA * 3 + 1], pzA = xyz[ptA * 3 + 2];
    float pxB = xyz[ptBc * 3 + 0], pyB = xyz[ptBc * 3 + 1], pzB = xyz[ptBc * 3 + 2];
    float axA = xyz[kidA * 3 + 0] - pxA, ayA = xyz[kidA * 3 + 1] - pyA, azA = xyz[kidA * 3 + 2] - pzA;
    float axB = xyz[kidB * 3 + 0] - pxB, ayB = xyz[kidB * 3 + 1] - pyB, azB = xyz[kidB * 3 + 2] - pzB;

    // ---- p0 rows in B-frag layout (registers)
    float p0A[16], p0B[16];
#pragma unroll
    for (int s = 0; s < 2; s++)
#pragma unroll
      for (int j = 0; j < 8; j++) {
        float4 w = w14[s * 32 + j * 4 + q];
        p0A[s * 8 + j] = fmaf(axA, w.x, fmaf(ayA, w.y, fmaf(azA, w.z, w.w)));
        p0B[s * 8 + j] = fmaf(axB, w.x, fmaf(ayB, w.y, fmaf(azB, w.z, w.w)));
      }
    S8U bp0A[2], bp0B[2], bplA[2], bplB[2];
#pragma unroll
    for (int s = 0; s < 2; s++)
#pragma unroll
      for (int jj = 0; jj < 4; jj++) {
        bp0A[s].u[jj] = pack2(p0A[s * 8 + 2 * jj], p0A[s * 8 + 2 * jj + 1]);
        bp0B[s].u[jj] = pack2(p0B[s * 8 + 2 * jj], p0B[s * 8 + 2 * jj + 1]);
      }
#pragma unroll
    for (int i = 0; i < 16; i++) { p0A[i] = rowmax16(p0A[i]); p0B[i] = rowmax16(p0B[i]); }
#pragma unroll
    for (int s = 0; s < 2; s++)
#pragma unroll
      for (int jj = 0; jj < 4; jj++) {
        bplA[s].u[jj] = pack2(p0A[s * 8 + 2 * jj], p0A[s * 8 + 2 * jj + 1]);
        bplB[s].u[jj] = pack2(p0B[s * 8 + 2 * jj], p0B[s * 8 + 2 * jj + 1]);
      }

    // ---- m2 -> p1 (sliced scratch) -> bpf frags
    short8 bpfA[2], bpfB[2];
#pragma unroll
    for (int s = 0; s < 2; s++) {
#pragma unroll
      for (int h = 0; h < 2; h++) {
        int mt = 2 * s + h;
        float4 bb = *(const float4*)&bias[mt * 16 + q * 4];
        f32x4 accA = {bb.x, bb.y, bb.z, bb.w};
        f32x4 accB = accA;
#pragma unroll
        for (int ks = 0; ks < 2; ks++) {
          short8 af = *(const short8*)(fr + (mt * 2 + ks) * 1024 + l * 16);
          accA = MFMA16(af, bp0A[ks].s, accA);
          accB = MFMA16(af, bp0B[ks].s, accB);
        }
        uint2 wA; wA.x = pack2(accA[0], accA[1]); wA.y = pack2(accA[2], accA[3]);
        uint2 wB; wB.x = pack2(accB[0], accB[1]); wB.y = pack2(accB[2], accB[3]);
        *(uint2*)(sA + m * 80 + h * 32 + q * 8) = wA;
        *(uint2*)(sB + m * 80 + h * 32 + q * 8) = wB;
      }
      bpfA[s] = *(const short8*)(sA + m * 80 + q * 16);
      bpfB[s] = *(const short8*)(sB + m * 80 + q * 16);
    }

    // ---- m3a -> gelu -> g (sliced scratch) -> bg frags
    short8 bgA[4], bgB[4];
#pragma unroll
    for (int s = 0; s < 4; s++) {
#pragma unroll
      for (int h = 0; h < 2; h++) {
        int mt = 2 * s + h;
        float4 bb = *(const float4*)&bias[64 + mt * 16 + q * 4];
        f32x4 accA = {bb.x, bb.y, bb.z, bb.w};
        f32x4 accB = accA;
#pragma unroll
        for (int ks = 0; ks < 4; ks++) {
          short8 af = *(const short8*)(fr + (8 + mt * 4 + ks) * 1024 + l * 16);
          short8 bA = (ks == 0) ? bpfA[0] : (ks == 1) ? bpfA[1] : (ks == 2) ? bplA[0].s : bplA[1].s;
          short8 bB = (ks == 0) ? bpfB[0] : (ks == 1) ? bpfB[1] : (ks == 2) ? bplB[0].s : bplB[1].s;
          accA = MFMA16(af, bA, accA);
          accB = MFMA16(af, bB, accB);
        }
        uint2 wA; wA.x = pack2(gelu_fast(accA[0]), gelu_fast(accA[1]));
        wA.y = pack2(gelu_fast(accA[2]), gelu_fast(accA[3]));
        uint2 wB; wB.x = pack2(gelu_fast(accB[0]), gelu_fast(accB[1]));
        wB.y = pack2(gelu_fast(accB[2]), gelu_fast(accB[3]));
        *(uint2*)(sA + m * 80 + h * 32 + q * 8) = wA;
        *(uint2*)(sB + m * 80 + h * 32 + q * 8) = wB;
      }
      bgA[s] = *(const short8*)(sA + m * 80 + q * 16);
      bgB[s] = *(const short8*)(sB + m * 80 + q * 16);
    }

    // ---- m3b + fused epilogue (pe in regs; lane's k-row = m, kid preloaded)
#pragma unroll
    for (int mt = 0; mt < 8; mt++) {
      float4 bb = *(const float4*)&bias[192 + mt * 16 + q * 4];
      f32x4 accA = {bb.x, bb.y, bb.z, bb.w};
      f32x4 accB = accA;
#pragma unroll
      for (int ks = 0; ks < 4; ks++) {
        short8 af = *(const short8*)(fr + (40 + mt * 4 + ks) * 1024 + l * 16);
        accA = MFMA16(af, bgA[ks], accA);
        accB = MFMA16(af, bgB[ks], accB);
      }
      {
        uint2 ga = *(const uint2*)(xp + (size_t)kidA * 64 + mt * 8 + q * 2);
        float v0 = bf_lo(ga.x) + accA[0];
        float v1 = bf_hi(ga.x) + accA[1];
        float v2 = bf_lo(ga.y) + accA[2];
        float v3 = bf_hi(ga.y) + accA[3];
        v0 = rowmax16(v0); v1 = rowmax16(v1); v2 = rowmax16(v2); v3 = rowmax16(v3);
        if (m == 0) {
          uint2 sf = *(const uint2*)(xp + (size_t)ptA * 64 + mt * 8 + q * 2);
          float4 o = make_float4(v0 - bf_lo(sf.x), v1 - bf_hi(sf.x),
                                 v2 - bf_lo(sf.y), v3 - bf_hi(sf.y));
          *(float4*)&xsmax[(size_t)ptA * COUT + mt * 16 + q * 4] = o;
        }
      }
      if (hasB) {
        uint2 gb = *(const uint2*)(xp + (size_t)kidB * 64 + mt * 8 + q * 2);
        float v0 = bf_lo(gb.x) + accB[0];
        float v1 = bf_hi(gb.x) + accB[1];
        float v2 = bf_lo(gb.y) + accB[2];
        float v3 = bf_hi(gb.y) + accB[3];
        v0 = rowmax16(v0); v1 = rowmax16(v1); v2 = rowmax16(v2); v3 = rowmax16(v3);
        if (m == 0) {
          uint2 sf = *(const uint2*)(xp + (size_t)ptB * 64 + mt * 8 + q * 2);
          float4 o = make_float4(v0 - bf_lo(sf.x), v1 - bf_hi(sf.x),
                                 v2 - bf_lo(sf.y), v3 - bf_hi(sf.y));
          *(float4*)&xsmax[(size_t)ptB * COUT + mt * 16 + q * 4] = o;
        }
      }
    }
  }
}

// ---------- BN stage 1: per-block partial sums ----------
__global__ __launch_bounds__(256) void k_bnstats(const float* __restrict__ xs,
                                                 float* __restrict__ part, int n) {
  int t = threadIdx.x;
  int c = t & 127;
  int h = t >> 7;
  float s = 0.f, s2 = 0.f;
  for (int r = blockIdx.x * 2 + h; r < n; r += gridDim.x * 2) {
    float v = xs[(size_t)r * COUT + c];
    s += v;
    s2 += v * v;
  }
  __shared__ float red[256];
  red[t] = s;
  __syncthreads();
  if (h == 0) part[blockIdx.x * 256 + c] = s + red[t + 128];
  __syncthreads();
  red[t] = s2;
  __syncthreads();
  if (h == 0) part[blockIdx.x * 256 + 128 + c] = s2 + red[t + 128];
}

// ---------- BN stage 2: finalize mean/invstd ----------
__global__ void k_bnfinal(const float* __restrict__ part, float* __restrict__ ms,
                          int n, int nb) {
  int c = threadIdx.x;  // 128 threads
  float s = 0.f, s2 = 0.f;
  for (int b = 0; b < nb; b++) {
    s += part[b * 256 + c];
    s2 += part[b * 256 + 128 + c];
  }
  float inv_n = 1.0f / (float)n;
  float mean = s * inv_n;
  float var = s2 * inv_n - mean * mean;
  ms[c] = mean;
  ms[128 + c] = rsqrtf(var + EPS);
}

// ---------- BN normalize ----------
__global__ __launch_bounds__(256) void k_bnnorm(const float* __restrict__ xs,
                                                const float* __restrict__ ms,
                                                const float* __restrict__ gamma,
                                                const float* __restrict__ beta,
                                                float* __restrict__ out, int n) {
  size_t i = (size_t)blockIdx.x * 256 + threadIdx.x;
  size_t total4 = (size_t)n * (COUT / 4);
  if (i >= total4) return;
  int c = (int)((i * 4) & (COUT - 1));
  float4 v = ((const float4*)xs)[i];
  float4 mn = *(const float4*)&ms[c];
  float4 iv = *(const float4*)&ms[128 + c];
  float4 gm = *(const float4*)&gamma[c];
  float4 bt = *(const float4*)&beta[c];
  float4 o;
  o.x = (v.x - mn.x) * iv.x * gm.x + bt.x;
  o.y = (v.y - mn.y) * iv.y * gm.y + bt.y;
  o.z = (v.z - mn.z) * iv.z * gm.z + bt.z;
  o.w = (v.w - mn.w) * iv.w * gm.w + bt.w;
  ((float4*)out)[i] = o;
}

// ---------- launch ----------
extern "C" void kernel_launch(void* const* d_in, const int* in_sizes, int n_in,
                              void* d_out, int out_size, void* d_ws, size_t ws_size,
                              hipStream_t stream) {
  const float* xyz = (const float*)d_in[0];
  const float* x = (const float*)d_in[1];
  const int* knn = (const int*)d_in[2];
  const float* W = (const float*)d_in[3];
  const float* m1w = (const float*)d_in[4];
  const float* m1b = (const float*)d_in[5];
  const float* m2w = (const float*)d_in[6];
  const float* m2b = (const float*)d_in[7];
  const float* m3aw = (const float*)d_in[8];
  const float* m3ab = (const float*)d_in[9];
  const float* m3bw = (const float*)d_in[10];
  const float* m3bb = (const float*)d_in[11];
  const float* gamma = (const float*)d_in[12];
  const float* beta = (const float*)d_in[13];
  float* out = (float*)d_out;

  int n = in_sizes[0] / 3;

  char* ws = (char*)d_ws;
  u32* xp = (u32*)ws;                       // n * 256 B
  size_t o1 = (((size_t)n * 256 + 255) & ~(size_t)255);
  float* xsm = (float*)(ws + o1);           // n * 512 B
  size_t o2 = o1 + (((size_t)n * 512 + 255) & ~(size_t)255);
  float* part = (float*)(ws + o2);          // 512 blocks * 256 floats
  size_t o3 = o2 + 524288;
  float* ms = (float*)(ws + o3);            // 256 floats (mean | invstd)

  k_proj<<<512, 256, 0, stream>>>(x, W, xp, n);
  k_lfa<<<256, 1024, 0, stream>>>(xyz, xp, knn, m1w, m1b, m2w, m2b,
                                  m3aw, m3ab, m3bw, m3bb, xsm, n);
  k_bnstats<<<512, 256, 0, stream>>>(xsm, part, n);
  k_bnfinal<<<1, 128, 0, stream>>>(part, ms, n, 512);
  k_bnnorm<<<(int)(((size_t)n * (COUT / 4) + 255) / 256), 256, 0, stream>>>(
      xsm, ms, gamma, beta, out, n);
}